// Round 7
// baseline (256.358 us; speedup 1.0000x reference)
//
#include <hip/hip_runtime.h>
#include <math.h>

// WaveLM: logits[b,t,v] = sum_{t'<t} g(id[b,t'], v)
// g(u,v) = 2 * sum_{i,j in 1..H} (A_u/i^dec)(A_v/j^dec) * sinc(2*(f_u*i - f_v*j))
// sinc(2d) = sin(2*pi*d)/(2*pi*d), sinc(0)=1
//
// R7 = R5's verified math (angle-addition + Montgomery batch inversion in
// packed-fp32 inline asm; monomial rational form of R6 was numerically wrong)
// + R6's scan fusion (wavelm_g writes per-8-token-segment sums to part;
// scanA = 64-segment exclusive scan; scanB = 8-step local scan; no atomics)
// + slot trims: u-side weights folded into duplicated (2*w*s, -2*w*c) planes,
// ptot-only guard tracking, in-place asm (+v) to avoid operand-copy movs,
// v-side sBw/cBw/nb precomputed in tab. Token loop unroll(1) keeps the body
// ~4 KB (R4 showed a fully-unrolled 8-token body busts L1I).

typedef float v2f __attribute__((ext_vector_type(2)));

constexpr int cB = 4, cT = 512, cV = 8000, cH = 7;
constexpr int GT = 8;                  // tokens per wavelm_g block = seglen
constexpr int NSEG = 64;               // cT / GT
// tab planes: 0-6 s | 7-13 c | 14-20 w | 21-27 b | 28-34 nb | 35-41 sBw | 42-48 cBw
constexpr int TABP  = 49;
constexpr int TABUP = 21;              // tabU (v2f): 0-6 aU | 7-13 2ws | 14-20 -2wc

__device__ __forceinline__ v2f pk_add(v2f a, v2f b) {
    v2f d; asm("v_pk_add_f32 %0, %1, %2" : "=v"(d) : "v"(a), "v"(b)); return d;
}
__device__ __forceinline__ v2f pk_mul(v2f a, v2f b) {
    v2f d; asm("v_pk_mul_f32 %0, %1, %2" : "=v"(d) : "v"(a), "v"(b)); return d;
}
__device__ __forceinline__ void pk_mul_ip(v2f& a, v2f b) {          // a *= b
    asm("v_pk_mul_f32 %0, %0, %1" : "+v"(a) : "v"(b));
}
__device__ __forceinline__ void pk_acc(v2f& acc, v2f a, v2f b) {    // acc += a*b
    asm("v_pk_fma_f32 %0, %1, %2, %0" : "+v"(acc) : "v"(a), "v"(b));
}

__global__ __launch_bounds__(256) void wavelm_tab(
    const float* __restrict__ freq, const float* __restrict__ amp,
    const float* __restrict__ decay_p, float* __restrict__ tab,
    v2f* __restrict__ tabU)
{
    const int v = blockIdx.x * 256 + threadIdx.x;
    if (v >= cV) return;
    const float decay = decay_p[0];
    const float f = freq[v], A = amp[v];
    const float p2 = __builtin_amdgcn_exp2f(-decay);
    const float p3 = __builtin_amdgcn_exp2f(-decay * 1.5849625007f);
    const float p5 = __builtin_amdgcn_exp2f(-decay * 2.3219280949f);
    const float p7 = __builtin_amdgcn_exp2f(-decay * 2.8073549221f);
    const float rp[7] = {1.f, p2, p3, p2*p2, p5, p2*p3, p7};
    const float INV2PI = 0.15915494309189535f;

    const float xr = f - rintf(f);
    const float s1 = __builtin_amdgcn_sinf(xr);
    const float c1 = __builtin_amdgcn_cosf(xr);
    float s = s1, c = c1;
#pragma unroll
    for (int k = 0; k < cH; ++k) {
        if (k) { const float sp = s, cp = c;
                 s = fmaf(sp, c1,  cp * s1);
                 c = fmaf(cp, c1, -(sp * s1)); }
        const float w = A * rp[k];
        const float b = f * (float)(k + 1);
        tab[(size_t)k * cV + v]        = s;
        tab[(size_t)(7 + k) * cV + v]  = c;
        tab[(size_t)(14 + k) * cV + v] = w;
        tab[(size_t)(21 + k) * cV + v] = b;
        tab[(size_t)(28 + k) * cV + v] = -b;
        tab[(size_t)(35 + k) * cV + v] = s * w * INV2PI;
        tab[(size_t)(42 + k) * cV + v] = c * w * INV2PI;
        v2f a2;  a2.x = b;             a2.y = b;
        v2f s2;  s2.x = 2.f * w * s;   s2.y = s2.x;
        v2f c2;  c2.x = -2.f * w * c;  c2.y = c2.x;
        tabU[(size_t)k * cV + v]        = a2;
        tabU[(size_t)(7 + k) * cV + v]  = s2;
        tabU[(size_t)(14 + k) * cV + v] = c2;
    }
}

__global__ __launch_bounds__(256) void wavelm_g(
    const int* __restrict__ ids, const float* __restrict__ tab,
    const v2f* __restrict__ tabU, float* __restrict__ out,
    float* __restrict__ part, int write_part)
{
    const int bt0 = blockIdx.y * GT;                 // tokens of one segment
    const int vh  = blockIdx.x * 256 + threadIdx.x;  // v-pair index
    const bool valid = (vh * 2 < cV);
    const int vc = valid ? vh : 0;

    const v2f* tp = (const v2f*)tab;                 // plane k at k*(cV/2)+vc
    v2f nb[cH], sBw[cH], cBw[cH];
#pragma unroll
    for (int j = 0; j < cH; ++j) {
        nb[j]  = tp[(size_t)(28 + j) * (cV/2) + vc];
        sBw[j] = tp[(size_t)(35 + j) * (cV/2) + vc];
        cBw[j] = tp[(size_t)(42 + j) * (cV/2) + vc];
    }

    v2f segacc = (v2f)0.f;
#pragma unroll 1
    for (int g = 0; g < GT; ++g) {
        const int bt = bt0 + g;
        const int id = ids[bt];                      // wave-uniform
        const v2f* tu = tabU + id;

        v2f accV = (v2f)0.f;
        float mn = 3.0e38f, mx = 0.0f;
#pragma unroll
        for (int i = 0; i < cH; ++i) {
            const v2f aUv  = tu[(size_t)i * cV];
            const v2f u2s  = tu[(size_t)(7 + i) * cV];
            const v2f u2cn = tu[(size_t)(14 + i) * cV];
            v2f d[cH], p[cH];
#pragma unroll
            for (int j = 0; j < cH; ++j) d[j] = pk_add(aUv, nb[j]);
            p[0] = d[0];
#pragma unroll
            for (int j = 1; j < cH; ++j) p[j] = pk_mul(p[j-1], d[j]);
            const float ptot = p[6].x * p[6].y;
            mn = fminf(mn, fabsf(ptot));
            mx = fmaxf(mx, fabsf(ptot));
            const float rt = __builtin_amdgcn_rcpf(ptot);
            v2f r;  r.x = rt * p[6].y;  r.y = rt * p[6].x;   // 1/p6 per comp
            // j = 6 (first) as mul, then 5..1, then j = 0 with r itself
            v2f inv = pk_mul(r, p[5]);
            v2f accS = pk_mul(cBw[6], inv);
            v2f accC = pk_mul(sBw[6], inv);
            pk_mul_ip(r, d[6]);
#pragma unroll
            for (int j = 5; j >= 1; --j) {
                inv = pk_mul(r, p[j-1]);
                pk_acc(accS, cBw[j], inv);
                pk_acc(accC, sBw[j], inv);
                pk_mul_ip(r, d[j]);
            }
            pk_acc(accS, cBw[0], r);
            pk_acc(accC, sBw[0], r);
            // accV += (2 wA sA)_i * accS + (-2 wA cA)_i * accC
            pk_acc(accV, u2s,  accS);
            pk_acc(accV, u2cn, accC);
        }

        // rare guarded redo: exact d==0 (v==id), product under/overflow, nan
        if (mn < 1e-37f || !(mx <= 1e37f) ||
            !(fabsf(accV.x) + fabsf(accV.y) < 1e37f)) {
            const float INV2PI = 0.15915494309189535f;
            float ax = 0.f, ay = 0.f;
#pragma unroll
            for (int i = 0; i < cH; ++i) {
                const float sAi = tab[(size_t)i * cV + id];
                const float cAi = tab[(size_t)(7 + i) * cV + id];
                const float wAi = tab[(size_t)(14 + i) * cV + id];
                const float aUi = tab[(size_t)(21 + i) * cV + id];
                float rx = 0.f, ry = 0.f;
#pragma unroll
                for (int j = 0; j < cH; ++j) {
                    const v2f sB = tp[(size_t)j * (cV/2) + vc];
                    const v2f cB = tp[(size_t)(7 + j) * (cV/2) + vc];
                    const v2f wB = tp[(size_t)(14 + j) * (cV/2) + vc];
                    const v2f bb = tp[(size_t)(21 + j) * (cV/2) + vc];
                    const float dx = aUi - bb.x;
                    const float dy = aUi - bb.y;
                    const float snx = fmaf(sAi, cB.x, -(cAi * sB.x));
                    const float sny = fmaf(sAi, cB.y, -(cAi * sB.y));
                    float qx = snx * INV2PI * __builtin_amdgcn_rcpf(dx);
                    float qy = sny * INV2PI * __builtin_amdgcn_rcpf(dy);
                    qx = (dx == 0.f) ? 1.f : qx;
                    qy = (dy == 0.f) ? 1.f : qy;
                    rx = fmaf(wB.x, qx, rx);
                    ry = fmaf(wB.y, qy, ry);
                }
                ax = fmaf(2.f * wAi, rx, ax);
                ay = fmaf(2.f * wAi, ry, ay);
            }
            accV.x = ax;  accV.y = ay;
        }

        if (valid)
            *(v2f*)(out + (size_t)bt * cV + (size_t)vh * 2) = accV;
        segacc = pk_add(segacc, accV);
    }

    if (valid && write_part)
        *(v2f*)(part + (size_t)blockIdx.y * cV + (size_t)vh * 2) = segacc;
}

// exclusive scan over NSEG segment sums per (b,v) column, in place
__global__ __launch_bounds__(256) void wavelm_scanA(float* __restrict__ part)
{
    const int g = blockIdx.x * 256 + threadIdx.x;
    if (g >= cB * cV) return;
    const int b = g / cV;
    const int v = g - b * cV;
    float acc = 0.f;
#pragma unroll 8
    for (int s = 0; s < NSEG; ++s) {
        const size_t idx = ((size_t)(b * NSEG + s)) * cV + v;
        const float t = part[idx];
        part[idx] = acc;
        acc += t;
    }
}

// local shifted scan of GT tokens with base from part
__global__ __launch_bounds__(256) void wavelm_scanB(
    float* __restrict__ out, const float* __restrict__ part)
{
    const int v = blockIdx.x * 256 + threadIdx.x;
    if (v >= cV) return;
    const int grp = blockIdx.y;                      // b*NSEG + seg
    float acc = part[(size_t)grp * cV + v];
    float* p = out + (size_t)grp * GT * cV + v;
#pragma unroll
    for (int k = 0; k < GT; ++k) {
        const float c = p[(size_t)k * cV];
        p[(size_t)k * cV] = acc;
        acc += c;
    }
}

// ---- fallback scans (small ws) ----
__global__ __launch_bounds__(256) void wavelm_seg(
    const float* __restrict__ out, float* __restrict__ segsum,
    int lgseg, int seglen)
{
    const int v = blockIdx.x * 256 + threadIdx.x;
    if (v >= cV) return;
    const int bs = blockIdx.y;
    const int b = bs >> lgseg, seg = bs & ((1 << lgseg) - 1);
    const float* p = out + ((size_t)b * cT + (size_t)seg * seglen) * cV + v;
    float a0 = 0.f, a1 = 0.f, a2 = 0.f, a3 = 0.f;
    for (int k = 0; k < seglen; k += 4) {
        a0 += p[(size_t)(k+0) * cV];  a1 += p[(size_t)(k+1) * cV];
        a2 += p[(size_t)(k+2) * cV];  a3 += p[(size_t)(k+3) * cV];
    }
    segsum[(size_t)bs * cV + v] = (a0 + a1) + (a2 + a3);
}

__global__ __launch_bounds__(256) void wavelm_scan2(
    float* __restrict__ out, const float* __restrict__ segsum,
    int lgseg, int seglen)
{
    const int v = blockIdx.x * 256 + threadIdx.x;
    if (v >= cV) return;
    const int bs = blockIdx.y;
    const int b = bs >> lgseg, seg = bs & ((1 << lgseg) - 1);
    const int nseg = 1 << lgseg;
    float base = 0.f;
    for (int sp = 0; sp < seg; ++sp)
        base += segsum[(size_t)(b * nseg + sp) * cV + v];
    float* p = out + ((size_t)b * cT + (size_t)seg * seglen) * cV + v;
    float acc = base;
#pragma unroll 8
    for (int k = 0; k < seglen; ++k) {
        const float c = p[(size_t)k * cV];
        p[(size_t)k * cV] = acc;
        acc += c;
    }
}

__global__ __launch_bounds__(256) void wavelm_scan(float* __restrict__ out)
{
    const int g = blockIdx.x * blockDim.x + threadIdx.x;
    if (g >= cB * cV) return;
    const int b = g / cV;
    const int v = g - b * cV;
    float* p = out + (size_t)b * cT * cV + v;
    float acc = 0.f;
#pragma unroll 8
    for (int t = 0; t < cT; ++t) {
        const float c = p[(size_t)t * cV];
        p[(size_t)t * cV] = acc;
        acc += c;
    }
}

extern "C" void kernel_launch(void* const* d_in, const int* in_sizes, int n_in,
                              void* d_out, int out_size, void* d_ws, size_t ws_size,
                              hipStream_t stream)
{
    const int*   ids  = (const int*)d_in[0];
    const float* freq = (const float*)d_in[1];
    const float* amp  = (const float*)d_in[2];
    const float* dec  = (const float*)d_in[3];
    float* out = (float*)d_out;

    float* tab  = (float*)d_ws;                           // 49 planes
    v2f*   tabU = (v2f*)(tab + (size_t)TABP * cV);        // 21 dup planes
    float* part = (float*)(tabU + (size_t)TABUP * cV);    // 256 x cV

    const size_t tab_b  = (size_t)TABP * cV * sizeof(float);
    const size_t tabu_b = (size_t)TABUP * cV * sizeof(v2f);
    const size_t part_b = (size_t)cB * NSEG * cV * sizeof(float);
    const int fast = (ws_size >= tab_b + tabu_b + part_b) ? 1 : 0;

    wavelm_tab<<<(cV + 255) / 256, 256, 0, stream>>>(freq, amp, dec, tab, tabU);

    dim3 grid((cV / 2 + 255) / 256, cB * cT / GT);        // 16 x 256
    wavelm_g<<<grid, dim3(256), 0, stream>>>(ids, tab, tabU, out, part, fast);

    if (fast) {
        const int nchains = cB * cV;
        wavelm_scanA<<<(nchains + 255) / 256, 256, 0, stream>>>(part);
        dim3 sb((cV + 255) / 256, cB * NSEG);             // 32 x 256
        wavelm_scanB<<<sb, dim3(256), 0, stream>>>(out, part);
    } else {
        float* segsum = part;
        int lgseg = 4;
        while (lgseg > 0 &&
               tab_b + tabu_b + ((size_t)cB << lgseg) * cV * sizeof(float) > ws_size)
            --lgseg;
        if (lgseg > 0) {
            const int nseg = 1 << lgseg, seglen = cT / nseg;
            dim3 sg((cV + 255) / 256, cB * nseg);
            wavelm_seg<<<sg, dim3(256), 0, stream>>>(out, segsum, lgseg, seglen);
            wavelm_scan2<<<sg, dim3(256), 0, stream>>>(out, segsum, lgseg, seglen);
        } else {
            const int nchains = cB * cV;
            wavelm_scan<<<(nchains + 255) / 256, dim3(256), 0, stream>>>(out);
        }
    }
}